// Round 9
// baseline (379.936 us; speedup 1.0000x reference)
//
#include <hip/hip_runtime.h>

typedef unsigned short u16;
typedef __attribute__((ext_vector_type(8))) short short8;
typedef __attribute__((ext_vector_type(4))) float f32x4;
typedef __attribute__((ext_vector_type(2))) float f32x2;

#define N_AGENTS 131072
#define HID 128
#define FUT 12
#define OBS 8

constexpr int AG = 8;              // 16-agent tiles per block
#define NEG_K  (-1.4426950408889634f)   // -log2(e)
#define NEG_2K (-2.8853900817779268f)   // -2*log2(e)

__device__ __forceinline__ u16 f2bf(float f) {   // RNE (setup only)
    union { float f; unsigned int i; } v; v.f = f;
    unsigned int u = v.i;
    return (u16)((u + 0x7fffu + ((u >> 16) & 1u)) >> 16);
}
__device__ __forceinline__ float bexp2(float x) {
#if __has_builtin(__builtin_amdgcn_exp2f)
    return __builtin_amdgcn_exp2f(x);
#else
    float r; asm("v_exp_f32 %0, %1" : "=v"(r) : "v"(x)); return r;
#endif
}
__device__ __forceinline__ float brcp(float x) {
#if __has_builtin(__builtin_amdgcn_rcpf)
    return __builtin_amdgcn_rcpf(x);
#else
    float r; asm("v_rcp_f32 %0, %1" : "=v"(r) : "v"(x)); return r;
#endif
}
__device__ __forceinline__ unsigned cvtpk(float lo, float hi) {  // 2x f32 -> packed bf16 (RNE)
    unsigned r; asm("v_cvt_pk_bf16_f32 %0, %1, %2" : "=v"(r) : "v"(lo), "v"(hi)); return r;
}

__launch_bounds__(256, 2)
__global__ void lstm_dec_kernel(const float* __restrict__ obs,
                                const float* __restrict__ h0g,
                                const float* __restrict__ Wih,
                                const float* __restrict__ Whh,
                                const float* __restrict__ bih,
                                const float* __restrict__ bhh,
                                const float* __restrict__ Wout,
                                const float* __restrict__ bout,
                                float* __restrict__ dout)
{
    __shared__ short8 hb[2][16][17];     // h double-buffer, rows padded to 272B
    __shared__ float  xt[16][2];
    __shared__ float  obs_s[32];
    __shared__ short8 outb_lds[4][64];   // W_out B-fragments, per (kf, lane)

    const int tid  = threadIdx.x;
    const int lane = tid & 63;
    const int wv   = tid >> 6;      // wave 0..3, owns hidden u in {wv*16+r, 64+wv*16+r}
    const int r    = lane & 15;
    const int kb   = lane >> 4;

    const float bout0 = bout[0];
    const float bout1 = bout[1];

    // gate scale folded into weights: i,f,o -> -K ; g -> -2K  (nt: 0=i,1=f,2=g,3=o)
    const float gscn[4] = {NEG_K, NEG_K, NEG_2K, NEG_K};

    // scaled effective bias, per (ct, nt):  col c = nt*128 + ct*64 + wv*16 + r
    float beff[2][4];
#pragma unroll
    for (int ct = 0; ct < 2; ++ct)
#pragma unroll
        for (int nt = 0; nt < 4; ++nt) {
            int c = nt * HID + ct * 64 + wv * 16 + r;
            float w0 = Wih[c * 2 + 0];
            float w1 = Wih[c * 2 + 1];
            beff[ct][nt] = (bih[c] + bhh[c] + w0 * bout0 + w1 * bout1) * gscn[nt];
        }

    // W_eff = (W_hh + W_ih @ W_out) * gsc  fragments (bf16): 128 VGPR
    short8 bfrag[2][4][4];
#pragma unroll
    for (int kf = 0; kf < 4; ++kf) {
        const int k0 = kf * 32 + kb * 8;
        float wo0[8], wo1[8];
#pragma unroll
        for (int j = 0; j < 8; ++j) {
            wo0[j] = Wout[0 * HID + k0 + j];
            wo1[j] = Wout[1 * HID + k0 + j];
        }
        if (wv == 0) {   // build out-projection B-frag in LDS (lane-dependent only)
            short8 ob;
#pragma unroll
            for (int j = 0; j < 8; ++j) {
                float sel = (r == 0) ? wo0[j] : ((r == 1) ? wo1[j] : 0.0f);
                ob[j] = (short)f2bf(sel);
            }
            outb_lds[kf][lane] = ob;
        }
#pragma unroll
        for (int ct = 0; ct < 2; ++ct)
#pragma unroll
            for (int nt = 0; nt < 4; ++nt) {
                int c = nt * HID + ct * 64 + wv * 16 + r;
                float s0 = Wih[c * 2 + 0] * gscn[nt];
                float s1 = Wih[c * 2 + 1] * gscn[nt];
                short8 tt;
#pragma unroll
                for (int j = 0; j < 8; ++j) {
                    float f = Whh[(size_t)c * HID + k0 + j] * gscn[nt]
                            + s0 * wo0[j] + s1 * wo1[j];
                    tt[j] = (short)f2bf(f);
                }
                bfrag[ct][nt][kf] = tt;
            }
    }

// ---- macros ----
#define LOADF(rb)                                                    \
    _Pragma("unroll")                                                \
    for (int kf = 0; kf < 4; ++kf)                                   \
        af[kf] = hb[rb][r][kf * 4 + kb];

#define GATES()                                                      \
    {                                                                \
        const f32x4 z4 = {0.f, 0.f, 0.f, 0.f};                       \
        _Pragma("unroll")                                            \
        for (int ct = 0; ct < 2; ++ct)                               \
            _Pragma("unroll")                                        \
            for (int nt = 0; nt < 4; ++nt)                           \
                acc[ct][nt] = __builtin_amdgcn_mfma_f32_16x16x32_bf16( \
                    af[0], bfrag[ct][nt][0], z4, 0, 0, 0);           \
        _Pragma("unroll")                                            \
        for (int kf = 1; kf < 4; ++kf)                               \
            _Pragma("unroll")                                        \
            for (int ct = 0; ct < 2; ++ct)                           \
                _Pragma("unroll")                                    \
                for (int nt = 0; nt < 4; ++nt)                       \
                    acc[ct][nt] = __builtin_amdgcn_mfma_f32_16x16x32_bf16( \
                        af[kf], bfrag[ct][nt][kf], acc[ct][nt], 0, 0, 0); \
    }

// out projection on wave 0 only; s==0 -> xt, else -> dout for step s-1
#define OUT_TILE(S)                                                  \
    if (wv == 0) {                                                   \
        const f32x4 z4o = {0.f, 0.f, 0.f, 0.f};                      \
        f32x4 oacc = __builtin_amdgcn_mfma_f32_16x16x32_bf16(        \
            af[0], outb_lds[0][lane], z4o, 0, 0, 0);                 \
        _Pragma("unroll")                                            \
        for (int kf = 1; kf < 4; ++kf)                               \
            oacc = __builtin_amdgcn_mfma_f32_16x16x32_bf16(          \
                af[kf], outb_lds[kf][lane], oacc, 0, 0, 0);          \
        if (r < 2) {                                                 \
            const float bo = (r == 0) ? bout0 : bout1;               \
            if ((S) == 0) {                                          \
                _Pragma("unroll")                                    \
                for (int q = 0; q < 4; ++q)                          \
                    xt[kb * 4 + q][r] = oacc[q] + bo;                \
            } else {                                                 \
                _Pragma("unroll")                                    \
                for (int q = 0; q < 4; ++q)                          \
                    dout[((size_t)((S) - 1) * N_AGENTS + A0 + kb * 4 + q) * 2 + r] = oacc[q] + bo; \
            }                                                        \
        }                                                            \
    }

// step-0 exact correction: gates += (x0 - x~0) @ (W_ih * gsc)^T
#define CORR()                                                       \
    {                                                                \
        float dx0[4], dx1[4];                                        \
        _Pragma("unroll")                                            \
        for (int q = 0; q < 4; ++q) {                                \
            dx0[q] = obs_s[(kb * 4 + q) * 2 + 0] - xt[kb * 4 + q][0]; \
            dx1[q] = obs_s[(kb * 4 + q) * 2 + 1] - xt[kb * 4 + q][1]; \
        }                                                            \
        _Pragma("unroll")                                            \
        for (int ct = 0; ct < 2; ++ct)                               \
            _Pragma("unroll")                                        \
            for (int nt = 0; nt < 4; ++nt) {                         \
                int c = nt * HID + ct * 64 + wv * 16 + r;            \
                float w0s = Wih[c * 2 + 0] * gscn[nt];               \
                float w1s = Wih[c * 2 + 1] * gscn[nt];               \
                _Pragma("unroll")                                    \
                for (int q = 0; q < 4; ++q)                          \
                    acc[ct][nt][q] += dx0[q] * w0s + dx1[q] * w1s;   \
            }                                                        \
    }

// packed pair-cell across the two col-tiles (same agent q), 14 trans / 2 cells
#define CELLP(q)                                                     \
    {                                                                \
        f32x2 Ei = {bexp2(acc[0][0][q] + beff[0][0]), bexp2(acc[1][0][q] + beff[1][0])}; \
        f32x2 Ef = {bexp2(acc[0][1][q] + beff[0][1]), bexp2(acc[1][1][q] + beff[1][1])}; \
        f32x2 Gg = {bexp2(acc[0][2][q] + beff[0][2]), bexp2(acc[1][2][q] + beff[1][2])}; \
        f32x2 Eo = {bexp2(acc[0][3][q] + beff[0][3]), bexp2(acc[1][3][q] + beff[1][3])}; \
        f32x2 c2 = {cf0[q], cf1[q]};                                 \
        f32x2 t1 = 1.0f + Ei;                                        \
        f32x2 t2 = 1.0f + Gg;                                        \
        f32x2 t3 = 1.0f + Ef;                                        \
        f32x2 t12 = t1 * t2;                                         \
        f32x2 num = t12 * c2 + t3 * (1.0f - Gg);                     \
        f32x2 den = t12 * t3;                                        \
        f32x2 R1 = {brcp(den.x), brcp(den.y)};                       \
        f32x2 cn = num * R1;                                         \
        cf0[q] = cn.x; cf1[q] = cn.y;                                \
        f32x2 ga = NEG_2K * cn;                                      \
        f32x2 Gc = {bexp2(ga.x), bexp2(ga.y)};                       \
        f32x2 u1 = (1.0f + Eo) * (1.0f + Gc);                        \
        f32x2 R2 = {brcp(u1.x), brcp(u1.y)};                         \
        f32x2 hv = (1.0f - Gc) * R2;                                 \
        unsigned pk = cvtpk(hv.x, hv.y);                             \
        hbase[(kb * 4 + q) * 136 + wv * 16 + r] = (u16)pk;           \
        hbase[(kb * 4 + q) * 136 + 64 + wv * 16 + r] = (u16)(pk >> 16); \
    }

#define ACTIV(wb)                                                    \
    {                                                                \
        u16* hbase = (u16*)&hb[wb][0][0];                            \
        CELLP(0) CELLP(1) CELLP(2) CELLP(3)                          \
    }

#pragma unroll 1
    for (int t = 0; t < AG; ++t) {
        const int A0 = (blockIdx.x * AG + t) * 16;

        // cooperative h0 preload -> hb[1] (bf16), 16 rows x 128 cols
        {
            int row = tid >> 4;            // 16 rows, 16 threads/row
            int c8  = (tid & 15) * 8;
            const float* hp = h0g + (size_t)(A0 + row) * HID + c8;
            f32x4 lo = *(const f32x4*)hp;
            f32x4 hi = *(const f32x4*)(hp + 4);
            short8 a;
            unsigned* ap = (unsigned*)&a;
            ap[0] = cvtpk(lo[0], lo[1]);
            ap[1] = cvtpk(lo[2], lo[3]);
            ap[2] = cvtpk(hi[0], hi[1]);
            ap[3] = cvtpk(hi[2], hi[3]);
            hb[1][row][tid & 15] = a;
        }
        if (tid < 32)
            obs_s[tid] = obs[((size_t)(OBS - 1) * N_AGENTS + A0) * 2 + tid];

        f32x4 cf0 = {0.f, 0.f, 0.f, 0.f};
        f32x4 cf1 = {0.f, 0.f, 0.f, 0.f};
        f32x4 acc[2][4];
        short8 af[4];
        __syncthreads();

        // ---------------- step 0 ----------------
        LOADF(1)
        GATES()
        OUT_TILE(0)
        __syncthreads();   // x~0 visible
        CORR()
        ACTIV(0)
        __syncthreads();

        // ---------------- steps 1..11 ----------------
#pragma unroll 1
        for (int s = 1; s < FUT; ++s) {
            LOADF((s - 1) & 1)
            GATES()
            OUT_TILE(s)
            ACTIV(s & 1)
            __syncthreads();
        }

        // ---------------- step 12: out only ----------------
        LOADF(1)
        OUT_TILE(FUT)
        __syncthreads();   // hb[1] reads done before next preload overwrites
    }
#undef LOADF
#undef GATES
#undef OUT_TILE
#undef CORR
#undef CELLP
#undef ACTIV
}

extern "C" void kernel_launch(void* const* d_in, const int* in_sizes, int n_in,
                              void* d_out, int out_size, void* d_ws, size_t ws_size,
                              hipStream_t stream) {
    const float* obs  = (const float*)d_in[0];
    // d_in[1] (fut_traj_rel) is unused by the reference
    const float* h0   = (const float*)d_in[2];
    const float* Wih  = (const float*)d_in[3];
    const float* Whh  = (const float*)d_in[4];
    const float* bih  = (const float*)d_in[5];
    const float* bhh  = (const float*)d_in[6];
    const float* Wout = (const float*)d_in[7];
    const float* bo   = (const float*)d_in[8];
    float* out = (float*)d_out;

    dim3 grid(N_AGENTS / (AG * 16));   // 1024 blocks of 256 threads
    lstm_dec_kernel<<<grid, 256, 0, stream>>>(obs, h0, Wih, Whh, bih, bhh, Wout, bo, out);
}

// Round 10
// 371.205 us; speedup vs baseline: 1.0235x; 1.0235x over previous
//
#include <hip/hip_runtime.h>

typedef unsigned short u16;
typedef __attribute__((ext_vector_type(8))) short short8;
typedef __attribute__((ext_vector_type(4))) float f32x4;
typedef __attribute__((ext_vector_type(2))) float f32x2;

#define N_AGENTS 131072
#define HID 128
#define FUT 12
#define OBS 8

constexpr int AG = 8;              // 16-agent tiles per block -> 128 agents/block
#define NEG_K  (-1.4426950408889634f)   // -log2(e)
#define NEG_2K (-2.8853900817779268f)   // -2*log2(e)

__device__ __forceinline__ u16 f2bf(float f) {   // RNE (setup only)
    union { float f; unsigned int i; } v; v.f = f;
    unsigned int u = v.i;
    return (u16)((u + 0x7fffu + ((u >> 16) & 1u)) >> 16);
}
__device__ __forceinline__ float bexp2(float x) {
#if __has_builtin(__builtin_amdgcn_exp2f)
    return __builtin_amdgcn_exp2f(x);
#else
    float r; asm("v_exp_f32 %0, %1" : "=v"(r) : "v"(x)); return r;
#endif
}
__device__ __forceinline__ float brcp(float x) {
#if __has_builtin(__builtin_amdgcn_rcpf)
    return __builtin_amdgcn_rcpf(x);
#else
    float r; asm("v_rcp_f32 %0, %1" : "=v"(r) : "v"(x)); return r;
#endif
}
__device__ __forceinline__ unsigned cvtpk(float lo, float hi) {  // 2x f32 -> packed bf16 (RNE)
    unsigned r; asm("v_cvt_pk_bf16_f32 %0, %1, %2" : "=v"(r) : "v"(lo), "v"(hi)); return r;
}

__launch_bounds__(512, 4)
__global__ void lstm_dec_kernel(const float* __restrict__ obs,
                                const float* __restrict__ h0g,
                                const float* __restrict__ Wih,
                                const float* __restrict__ Whh,
                                const float* __restrict__ bih,
                                const float* __restrict__ bhh,
                                const float* __restrict__ Wout,
                                const float* __restrict__ bout,
                                float* __restrict__ dout)
{
    __shared__ short8 hb[2][16][17];     // h double-buffer, rows padded to 272B
    __shared__ float  xt[16][2];
    __shared__ float  ot[FUT][16][2];    // staged outputs (384 floats)
    __shared__ short8 outb_lds[4][64];   // W_out B-fragments per (kf, lane)

    const int tid  = threadIdx.x;
    const int lane = tid & 63;
    const int wv   = tid >> 6;      // wave 0..7, owns hidden [16*wv, 16*wv+16)
    const int r    = lane & 15;
    const int kb   = lane >> 4;

    const float bout0 = bout[0];
    const float bout1 = bout[1];
    const float bo_sc = (r == 0) ? bout0 : ((r == 1) ? bout1 : 0.0f);

    // gate scale folded into weights: i,f,o -> -K ; g -> -2K  (nt: 0=i,1=f,2=g,3=o)
    const float gscn[4] = {NEG_K, NEG_K, NEG_2K, NEG_K};

    // scaled effective bias (added in-cell), 4 regs
    float beff[4];
#pragma unroll
    for (int nt = 0; nt < 4; ++nt) {
        int c = nt * HID + wv * 16 + r;
        float w0 = Wih[c * 2 + 0];
        float w1 = Wih[c * 2 + 1];
        beff[nt] = (bih[c] + bhh[c] + w0 * bout0 + w1 * bout1) * gscn[nt];
    }

    // W_eff = (W_hh + W_ih @ W_out) * gsc  fragments (bf16): 64 VGPR
    short8 bfrag[4][4];
#pragma unroll
    for (int kf = 0; kf < 4; ++kf) {
        const int k0 = kf * 32 + kb * 8;
        float wo0[8], wo1[8];
#pragma unroll
        for (int j = 0; j < 8; ++j) {
            wo0[j] = Wout[0 * HID + k0 + j];
            wo1[j] = Wout[1 * HID + k0 + j];
        }
        if (wv == 0) {   // out-projection B-frag -> LDS
            short8 ob;
#pragma unroll
            for (int j = 0; j < 8; ++j) {
                float sel = (r == 0) ? wo0[j] : ((r == 1) ? wo1[j] : 0.0f);
                ob[j] = (short)f2bf(sel);
            }
            outb_lds[kf][lane] = ob;
        }
#pragma unroll
        for (int nt = 0; nt < 4; ++nt) {
            int c = nt * HID + wv * 16 + r;
            float s0 = Wih[c * 2 + 0] * gscn[nt];
            float s1 = Wih[c * 2 + 1] * gscn[nt];
            short8 tt;
#pragma unroll
            for (int j = 0; j < 8; ++j) {
                float f = Whh[(size_t)c * HID + k0 + j] * gscn[nt]
                        + s0 * wo0[j] + s1 * wo1[j];
                tt[j] = (short)f2bf(f);
            }
            bfrag[nt][kf] = tt;
        }
    }

// ---- macros ----
#define LOADF(rb)                                                    \
    _Pragma("unroll")                                                \
    for (int kf = 0; kf < 4; ++kf)                                   \
        af[kf] = hb[rb][r][kf * 4 + kb];

#define GATES()                                                      \
    {                                                                \
        const f32x4 z4 = {0.f, 0.f, 0.f, 0.f};                       \
        _Pragma("unroll")                                            \
        for (int nt = 0; nt < 4; ++nt)                               \
            acc[nt] = __builtin_amdgcn_mfma_f32_16x16x32_bf16(       \
                af[0], bfrag[nt][0], z4, 0, 0, 0);                   \
        _Pragma("unroll")                                            \
        for (int kf = 1; kf < 4; ++kf)                               \
            _Pragma("unroll")                                        \
            for (int nt = 0; nt < 4; ++nt)                           \
                acc[nt] = __builtin_amdgcn_mfma_f32_16x16x32_bf16(   \
                    af[kf], bfrag[nt][kf], acc[nt], 0, 0, 0);        \
    }

// out projection on wave 0 only; s==0 -> xt, else -> ot[s-1]
#define OUT_TILE(dst_expr)                                           \
    if (wv == 0) {                                                   \
        const f32x4 z4o = {0.f, 0.f, 0.f, 0.f};                      \
        f32x4 oacc = __builtin_amdgcn_mfma_f32_16x16x32_bf16(        \
            af[0], outb_lds[0][lane], z4o, 0, 0, 0);                 \
        _Pragma("unroll")                                            \
        for (int kf = 1; kf < 4; ++kf)                               \
            oacc = __builtin_amdgcn_mfma_f32_16x16x32_bf16(          \
                af[kf], outb_lds[kf][lane], oacc, 0, 0, 0);          \
        if (r < 2) {                                                 \
            _Pragma("unroll")                                        \
            for (int q = 0; q < 4; ++q)                              \
                (dst_expr)[kb * 4 + q][r] = oacc[q] + bo_sc;         \
        }                                                            \
    }

// step-0 exact correction; W_ih reloaded (L2-hot, once per tile)
#define CORR()                                                       \
    _Pragma("unroll")                                                \
    for (int nt = 0; nt < 4; ++nt) {                                 \
        int c = nt * HID + wv * 16 + r;                              \
        float w0s = Wih[c * 2 + 0] * gscn[nt];                       \
        float w1s = Wih[c * 2 + 1] * gscn[nt];                       \
        _Pragma("unroll")                                            \
        for (int q = 0; q < 4; ++q) {                                \
            float dx0 = ox0[q] - xt[kb * 4 + q][0];                  \
            float dx1 = ox1[q] - xt[kb * 4 + q][1];                  \
            acc[nt][q] += dx0 * w0s + dx1 * w1s;                     \
        }                                                            \
    }

// packed pair-cell (q pair within tile), 14 trans / 2 cells, beff in-cell
#define CELLP(qa, qb)                                                \
    {                                                                \
        f32x2 Ei = {bexp2(acc[0][qa] + beff[0]), bexp2(acc[0][qb] + beff[0])}; \
        f32x2 Ef = {bexp2(acc[1][qa] + beff[1]), bexp2(acc[1][qb] + beff[1])}; \
        f32x2 Gg = {bexp2(acc[2][qa] + beff[2]), bexp2(acc[2][qb] + beff[2])}; \
        f32x2 Eo = {bexp2(acc[3][qa] + beff[3]), bexp2(acc[3][qb] + beff[3])}; \
        f32x2 c2 = {cf[qa], cf[qb]};                                 \
        f32x2 t1 = 1.0f + Ei;                                        \
        f32x2 t2 = 1.0f + Gg;                                        \
        f32x2 t3 = 1.0f + Ef;                                        \
        f32x2 t12 = t1 * t2;                                         \
        f32x2 num = t12 * c2 + t3 * (1.0f - Gg);                     \
        f32x2 den = t12 * t3;                                        \
        f32x2 R1 = {brcp(den.x), brcp(den.y)};                       \
        f32x2 cn = num * R1;                                         \
        cf[qa] = cn.x; cf[qb] = cn.y;                                \
        f32x2 ga = NEG_2K * cn;                                      \
        f32x2 Gc = {bexp2(ga.x), bexp2(ga.y)};                       \
        f32x2 u1 = (1.0f + Eo) * (1.0f + Gc);                        \
        f32x2 R2 = {brcp(u1.x), brcp(u1.y)};                         \
        f32x2 hv = (1.0f - Gc) * R2;                                 \
        unsigned pk = cvtpk(hv.x, hv.y);                             \
        hbase[(kb * 4 + qa) * 136 + wv * 16 + r] = (u16)pk;          \
        hbase[(kb * 4 + qb) * 136 + wv * 16 + r] = (u16)(pk >> 16);  \
    }

#define ACTIV(wb)                                                    \
    {                                                                \
        u16* hbase = (u16*)&hb[wb][0][0];                            \
        CELLP(0, 1) CELLP(2, 3)                                      \
    }

#pragma unroll 1
    for (int t = 0; t < AG; ++t) {
        const int A0 = (blockIdx.x * AG + t) * 16;

        // cooperative h0 preload -> hb[1] (bf16), 16 rows x 128 cols, 512 threads
        {
            int row = tid >> 5;            // 16 rows, 32 threads/row
            int c4  = (tid & 31) * 4;
            const float* hp = h0g + (size_t)(A0 + row) * HID + c4;
            f32x4 v = *(const f32x4*)hp;
            unsigned* dst = (unsigned*)&hb[1][row][0] + (tid & 31) * 2;
            dst[0] = cvtpk(v[0], v[1]);
            dst[1] = cvtpk(v[2], v[3]);
        }
        // obs x0 prefetch
        float ox0[4], ox1[4];
#pragma unroll
        for (int q = 0; q < 4; ++q) {
            const float* op = obs + ((size_t)(OBS - 1) * N_AGENTS + A0 + kb * 4 + q) * 2;
            ox0[q] = op[0];
            ox1[q] = op[1];
        }
        f32x4 cf = {0.f, 0.f, 0.f, 0.f};
        f32x4 acc[4];
        short8 af[4];
        __syncthreads();

        // ---------------- step 0 ----------------
        LOADF(1)
        GATES()
        OUT_TILE(xt)
        __syncthreads();   // x~0 visible
        CORR()
        ACTIV(0)
        __syncthreads();

        // ---------------- steps 1..11 ----------------
#pragma unroll 1
        for (int s = 1; s < FUT; ++s) {
            LOADF((s - 1) & 1)
            GATES()
            OUT_TILE(ot[s - 1])
            ACTIV(s & 1)
            __syncthreads();
        }

        // ---------------- step 12: out only ----------------
        LOADF(1)
        OUT_TILE(ot[FUT - 1])
        __syncthreads();

        // ---------------- coalesced flush: 384 floats ----------------
        if (tid < FUT * 32) {
            const float* otf = &ot[0][0][0];
            dout[((size_t)(tid >> 5) * N_AGENTS + A0) * 2 + (tid & 31)] = otf[tid];
        }
        // next ot write (s=1 OUT of next tile) is >=2 barriers away — safe
    }
#undef LOADF
#undef GATES
#undef OUT_TILE
#undef CORR
#undef CELLP
#undef ACTIV
}

extern "C" void kernel_launch(void* const* d_in, const int* in_sizes, int n_in,
                              void* d_out, int out_size, void* d_ws, size_t ws_size,
                              hipStream_t stream) {
    const float* obs  = (const float*)d_in[0];
    // d_in[1] (fut_traj_rel) is unused by the reference
    const float* h0   = (const float*)d_in[2];
    const float* Wih  = (const float*)d_in[3];
    const float* Whh  = (const float*)d_in[4];
    const float* bih  = (const float*)d_in[5];
    const float* bhh  = (const float*)d_in[6];
    const float* Wout = (const float*)d_in[7];
    const float* bo   = (const float*)d_in[8];
    float* out = (float*)d_out;

    dim3 grid(N_AGENTS / (AG * 16));   // 1024 blocks of 512 threads
    lstm_dec_kernel<<<grid, 512, 0, stream>>>(obs, h0, Wih, Whh, bih, bhh, Wout, bo, out);
}

// Round 11
// 297.306 us; speedup vs baseline: 1.2779x; 1.2486x over previous
//
#include <hip/hip_runtime.h>

typedef unsigned short u16;
typedef __attribute__((ext_vector_type(8))) short short8;
typedef __attribute__((ext_vector_type(4))) float f32x4;
typedef __attribute__((ext_vector_type(2))) float f32x2;

#define N_AGENTS 131072
#define HID 128
#define FUT 12
#define OBS 8

constexpr int PAIRS = 4;   // 32-agent pair-tiles per block -> 128 agents/block
#define NEG_K  (-1.4426950408889634f)   // -log2(e)
#define NEG_2K (-2.8853900817779268f)   // -2*log2(e)

__device__ __forceinline__ u16 f2bf(float f) {   // RNE (setup only)
    union { float f; unsigned int i; } v; v.f = f;
    unsigned int u = v.i;
    return (u16)((u + 0x7fffu + ((u >> 16) & 1u)) >> 16);
}
__device__ __forceinline__ float bexp2(float x) {
#if __has_builtin(__builtin_amdgcn_exp2f)
    return __builtin_amdgcn_exp2f(x);
#else
    float r; asm("v_exp_f32 %0, %1" : "=v"(r) : "v"(x)); return r;
#endif
}
__device__ __forceinline__ float brcp(float x) {
#if __has_builtin(__builtin_amdgcn_rcpf)
    return __builtin_amdgcn_rcpf(x);
#else
    float r; asm("v_rcp_f32 %0, %1" : "=v"(r) : "v"(x)); return r;
#endif
}
__device__ __forceinline__ unsigned cvtpk(float lo, float hi) {  // 2x f32 -> packed bf16 (RNE)
    unsigned r; asm("v_cvt_pk_bf16_f32 %0, %1, %2" : "=v"(r) : "v"(lo), "v"(hi)); return r;
}

__launch_bounds__(512, 2)
__global__ void lstm_dec_kernel(const float* __restrict__ obs,
                                const float* __restrict__ h0g,
                                const float* __restrict__ Wih,
                                const float* __restrict__ Whh,
                                const float* __restrict__ bih,
                                const float* __restrict__ bhh,
                                const float* __restrict__ Wout,
                                const float* __restrict__ bout,
                                float* __restrict__ dout)
{
    __shared__ short8 hb[2][32][17];     // rows 0-15: tile A, 16-31: tile B
    __shared__ float  xt[32][2];
    __shared__ float  ot[FUT][32][2];

    const int tid  = threadIdx.x;
    const int lane = tid & 63;
    const int wv   = tid >> 6;      // wave 0..7, owns hidden [16*wv, 16*wv+16)
    const int r    = lane & 15;
    const int kb   = lane >> 4;

    const float bout0 = bout[0];
    const float bout1 = bout[1];

    // gate scale folded into weights: i,f,o -> -K ; g -> -2K  (nt: 0=i,1=f,2=g,3=o)
    const float gsc[4] = {NEG_K, NEG_K, NEG_2K, NEG_K};

    float wihs0[4], wihs1[4];
    f32x4 accInit[4];                // scaled bias as MFMA C-in
#pragma unroll
    for (int nt = 0; nt < 4; ++nt) {
        int c = nt * HID + wv * 16 + r;
        float w0 = Wih[c * 2 + 0];
        float w1 = Wih[c * 2 + 1];
        float be = (bih[c] + bhh[c] + w0 * bout0 + w1 * bout1) * gsc[nt];
        wihs0[nt] = w0 * gsc[nt];
        wihs1[nt] = w1 * gsc[nt];
        accInit[nt] = f32x4{be, be, be, be};
    }
    const float bo = (r == 0) ? bout0 : ((r == 1) ? bout1 : 0.0f);
    const f32x4 oInit = {bo, bo, bo, bo};

    // W_eff = (W_hh + W_ih @ W_out) * gsc  fragments (bf16): 64 VGPR; outb: 16
    short8 bfrag[4][4];
    short8 outb[4];
#pragma unroll
    for (int kf = 0; kf < 4; ++kf) {
        const int k0 = kf * 32 + kb * 8;
        float wo0[8], wo1[8];
        short8 ob;
#pragma unroll
        for (int j = 0; j < 8; ++j) {
            wo0[j] = Wout[0 * HID + k0 + j];
            wo1[j] = Wout[1 * HID + k0 + j];
            float sel = (r == 0) ? wo0[j] : ((r == 1) ? wo1[j] : 0.0f);
            ob[j] = (short)f2bf(sel);
        }
        outb[kf] = ob;
#pragma unroll
        for (int nt = 0; nt < 4; ++nt) {
            int c = nt * HID + wv * 16 + r;
            float s0 = wihs0[nt], s1 = wihs1[nt];   // already scaled
            short8 tt;
#pragma unroll
            for (int j = 0; j < 8; ++j) {
                float f = Whh[(size_t)c * HID + k0 + j] * gsc[nt]
                        + s0 * wo0[j] + s1 * wo1[j];
                tt[j] = (short)f2bf(f);
            }
            bfrag[nt][kf] = tt;
        }
    }

// ---- macros ----
#define LOADF(a, rb, rowoff)                                         \
    _Pragma("unroll")                                                \
    for (int kf = 0; kf < 4; ++kf)                                   \
        a[kf] = hb[rb][(rowoff) + r][kf * 4 + kb];

#define GATES_ONE(acc, a)                                            \
    _Pragma("unroll")                                                \
    for (int nt = 0; nt < 4; ++nt)                                   \
        acc[nt] = __builtin_amdgcn_mfma_f32_16x16x32_bf16(           \
            a[0], bfrag[nt][0], accInit[nt], 0, 0, 0);               \
    _Pragma("unroll")                                                \
    for (int kf = 1; kf < 4; ++kf)                                   \
        _Pragma("unroll")                                            \
        for (int nt = 0; nt < 4; ++nt)                               \
            acc[nt] = __builtin_amdgcn_mfma_f32_16x16x32_bf16(       \
                a[kf], bfrag[nt][kf], acc[nt], 0, 0, 0);

#define OUT_ONE(whichwv, a, dst_expr, rowoff)                        \
    if (wv == (whichwv)) {                                           \
        f32x4 oacc = __builtin_amdgcn_mfma_f32_16x16x32_bf16(        \
            a[0], outb[0], oInit, 0, 0, 0);                          \
        _Pragma("unroll")                                            \
        for (int kf = 1; kf < 4; ++kf)                               \
            oacc = __builtin_amdgcn_mfma_f32_16x16x32_bf16(          \
                a[kf], outb[kf], oacc, 0, 0, 0);                     \
        if (r < 2) {                                                 \
            _Pragma("unroll")                                        \
            for (int q = 0; q < 4; ++q)                              \
                (dst_expr)[(rowoff) + kb * 4 + q][r] = oacc[q];      \
        }                                                            \
    }

// packed pair-cell within a tile (q pair) — math identical to R7/R8
#define CELLP(acc, cf, qa, qb, rowoff)                               \
    {                                                                \
        f32x2 Ei = {bexp2(acc[0][qa]), bexp2(acc[0][qb])};           \
        f32x2 Ef = {bexp2(acc[1][qa]), bexp2(acc[1][qb])};           \
        f32x2 Gg = {bexp2(acc[2][qa]), bexp2(acc[2][qb])};           \
        f32x2 Eo = {bexp2(acc[3][qa]), bexp2(acc[3][qb])};           \
        f32x2 c2 = {cf[qa], cf[qb]};                                 \
        f32x2 t1 = 1.0f + Ei;                                        \
        f32x2 t2 = 1.0f + Gg;                                        \
        f32x2 t3 = 1.0f + Ef;                                        \
        f32x2 t12 = t1 * t2;                                         \
        f32x2 num = t12 * c2 + t3 * (1.0f - Gg);                     \
        f32x2 den = t12 * t3;                                        \
        f32x2 R1 = {brcp(den.x), brcp(den.y)};                       \
        f32x2 cn = num * R1;                                         \
        cf[qa] = cn.x; cf[qb] = cn.y;                                \
        f32x2 ga = NEG_2K * cn;                                      \
        f32x2 Gc = {bexp2(ga.x), bexp2(ga.y)};                       \
        f32x2 u1 = (1.0f + Eo) * (1.0f + Gc);                        \
        f32x2 R2 = {brcp(u1.x), brcp(u1.y)};                         \
        f32x2 hv = (1.0f - Gc) * R2;                                 \
        unsigned pk = cvtpk(hv.x, hv.y);                             \
        hbase[((rowoff) + kb * 4 + qa) * 136 + hcol] = (u16)pk;      \
        hbase[((rowoff) + kb * 4 + qb) * 136 + hcol] = (u16)(pk >> 16); \
    }

#define ACTIV_ONE(acc, cf, wb, rowoff)                               \
    {                                                                \
        u16* hbase = (u16*)&hb[wb][0][0];                            \
        const int hcol = wv * 16 + r;                                \
        CELLP(acc, cf, 0, 1, rowoff)                                 \
        CELLP(acc, cf, 2, 3, rowoff)                                 \
    }

#define CORR(acc, ox0v, ox1v, rowoff)                                \
    _Pragma("unroll")                                                \
    for (int q = 0; q < 4; ++q) {                                    \
        float dx0 = ox0v[q] - xt[(rowoff) + kb * 4 + q][0];          \
        float dx1 = ox1v[q] - xt[(rowoff) + kb * 4 + q][1];          \
        _Pragma("unroll")                                            \
        for (int nt = 0; nt < 4; ++nt)                               \
            acc[nt][q] += dx0 * wihs0[nt] + dx1 * wihs1[nt];         \
    }

#pragma unroll 1
    for (int t = 0; t < PAIRS; ++t) {
        const int A0 = (blockIdx.x * PAIRS + t) * 32;

        // cooperative h0 preload -> hb[1] (bf16), 32 rows x 128 cols
        {
            int row = tid >> 4;            // 32 rows, 16 threads/row
            int c8  = (tid & 15) * 8;
            const float* hp = h0g + (size_t)(A0 + row) * HID + c8;
            f32x4 lo = *(const f32x4*)hp;
            f32x4 hi = *(const f32x4*)(hp + 4);
            short8 a;
            unsigned* ap = (unsigned*)&a;
            ap[0] = cvtpk(lo[0], lo[1]);
            ap[1] = cvtpk(lo[2], lo[3]);
            ap[2] = cvtpk(hi[0], hi[1]);
            ap[3] = cvtpk(hi[2], hi[3]);
            hb[1][row][tid & 15] = a;
        }
        // obs x0 prefetch (tile A: rows 0-15, tile B: rows 16-31)
        float oxA0[4], oxA1[4], oxB0[4], oxB1[4];
#pragma unroll
        for (int q = 0; q < 4; ++q) {
            const float* opA = obs + ((size_t)(OBS - 1) * N_AGENTS + A0 + kb * 4 + q) * 2;
            const float* opB = obs + ((size_t)(OBS - 1) * N_AGENTS + A0 + 16 + kb * 4 + q) * 2;
            oxA0[q] = opA[0]; oxA1[q] = opA[1];
            oxB0[q] = opB[0]; oxB1[q] = opB[1];
        }
        f32x4 cfA = {0.f, 0.f, 0.f, 0.f};
        f32x4 cfB = {0.f, 0.f, 0.f, 0.f};
        f32x4 accA[4], accB[4];
        __syncthreads();

        // ---- phase 0: GATES(A,0) + x~0(A)  (no ACTIV available yet) ----
        {
            short8 aA[4];
            LOADF(aA, 1, 0)
            GATES_ONE(accA, aA)
            OUT_ONE(0, aA, xt, 0)
        }
        __syncthreads();

        // ---- phase 1: corr(A)+ACTIV(A,0) first, then GATES(B,0)+x~0(B) ----
        {
            short8 aB[4];
            LOADF(aB, 1, 16)
            CORR(accA, oxA0, oxA1, 0)
            ACTIV_ONE(accA, cfA, 0, 0)
            GATES_ONE(accB, aB)
            OUT_ONE(1, aB, xt, 16)
        }
        __syncthreads();

        // ---- steps 1..11: anti-phase, ACTIV-first ordering ----
#pragma unroll 2
        for (int s = 1; s < FUT; ++s) {
            const int rp = (s - 1) & 1;   // read parity
            const int wp = s & 1;         // write parity
            { // phase 2s: ACTIV(B,s-1) || GATES(A,s)
                short8 aA[4];
                LOADF(aA, rp, 0)
                if (s == 1) { CORR(accB, oxB0, oxB1, 16) }
                ACTIV_ONE(accB, cfB, rp, 16)
                GATES_ONE(accA, aA)
                OUT_ONE(0, aA, ot[s - 1], 0)
            }
            __syncthreads();
            { // phase 2s+1: ACTIV(A,s) || GATES(B,s)
                short8 aB[4];
                LOADF(aB, rp, 16)
                ACTIV_ONE(accA, cfA, wp, 0)
                GATES_ONE(accB, aB)
                OUT_ONE(1, aB, ot[s - 1], 16)
            }
            __syncthreads();
        }

        // ---- phase 24: ACTIV(B,11) first, then OUT(A,12) ----
        {
            short8 aA[4];
            LOADF(aA, 1, 0)
            ACTIV_ONE(accB, cfB, 1, 16)
            OUT_ONE(0, aA, ot[FUT - 1], 0)
        }
        __syncthreads();

        // ---- phase 25: OUT(B,12) ----
        {
            short8 aB[4];
            LOADF(aB, 1, 16)
            OUT_ONE(1, aB, ot[FUT - 1], 16)
        }
        __syncthreads();

        // ---- coalesced flush: 768 floats ----
        {
            const float* otf = &ot[0][0][0];
            int idx = tid;                      // 0..511
            dout[((size_t)(idx >> 6) * N_AGENTS + A0) * 2 + (idx & 63)] = otf[idx];
            idx = tid + 512;
            if (idx < FUT * 64)
                dout[((size_t)(idx >> 6) * N_AGENTS + A0) * 2 + (idx & 63)] = otf[idx];
        }
        // next ot write (phase 2 of next pair) is >=2 barriers away — safe
    }
#undef LOADF
#undef GATES_ONE
#undef OUT_ONE
#undef CELLP
#undef ACTIV_ONE
#undef CORR
}

extern "C" void kernel_launch(void* const* d_in, const int* in_sizes, int n_in,
                              void* d_out, int out_size, void* d_ws, size_t ws_size,
                              hipStream_t stream) {
    const float* obs  = (const float*)d_in[0];
    // d_in[1] (fut_traj_rel) is unused by the reference
    const float* h0   = (const float*)d_in[2];
    const float* Wih  = (const float*)d_in[3];
    const float* Whh  = (const float*)d_in[4];
    const float* bih  = (const float*)d_in[5];
    const float* bhh  = (const float*)d_in[6];
    const float* Wout = (const float*)d_in[7];
    const float* bo   = (const float*)d_in[8];
    float* out = (float*)d_out;

    dim3 grid(N_AGENTS / (PAIRS * 32));   // 1024 blocks of 512 threads
    lstm_dec_kernel<<<grid, 512, 0, stream>>>(obs, h0, Wih, Whh, bih, bhh, Wout, bo, out);
}